// Round 1
// baseline (167.809 us; speedup 1.0000x reference)
//
#include <hip/hip_runtime.h>

// RGCNConv: out = sum_r ((A * [edge==r]) @ x) @ W_r + bias
// N=4096, IN=OUT=256, R=8.
// Plan:
//   k_init : out[i][o] = bias[o]
//   k_y    : y_t[o][j*8+r] = (x @ W_r)[j][o]  (bf16, in ws, 16 MB)
//   k_main : out[i][o] += sum_j A[i][j] * y_t[o][j*8 + e[i][j]]
//            as MFMA GEMM with one-hot expanded A operand (K_eff = 4096*8),
//            K-split x8 with f32 atomicAdd.

#define NN 4096
#define CH 256

typedef __attribute__((ext_vector_type(8))) short  s16x8;   // 8 bf16 (4 VGPR) MFMA frag
typedef __attribute__((ext_vector_type(4))) float  fx4;
typedef __attribute__((ext_vector_type(4))) int    ix4;
typedef __attribute__((ext_vector_type(4))) unsigned int ux4;

__device__ __forceinline__ unsigned short f2bf(float f) {
  union { float f; unsigned int u; } v; v.f = f;
  unsigned int r = v.u + 0x7fffu + ((v.u >> 16) & 1u);  // RNE
  return (unsigned short)(r >> 16);
}

// ---------------- init: out = bias ----------------
__global__ void k_init(const float* __restrict__ bias, float* __restrict__ out) {
  int idx = blockIdx.x * 256 + threadIdx.x;
  out[idx] = bias[idx & (CH - 1)];
}

// ---------------- y_t[o][j*8+r] = sum_k x[j][k] * W[r][k][o] ----------------
// grid (64 jtiles, 16 otiles), 256 thr (4 waves). Block tile: j 64 x n' 128,
// n' = (o-o0)*8 + r. K=256. W tile in LDS [n'=128][k=256] bf16, 16B-granule
// XOR swizzle (granule ^ (row&7)).
__global__ __launch_bounds__(256) void k_y(const float* __restrict__ x,
                                           const float* __restrict__ W,
                                           unsigned short* __restrict__ yt) {
  __shared__ unsigned short Wl[128 * 256];  // 64 KB
  const int t  = threadIdx.x;
  const int j0 = blockIdx.x * 64;
  const int o0 = blockIdx.y * 16;

  // stage W: thread -> (r = t>>5, kc = t&31), k = kc*8+u, 16 o's per k
  {
    const int r = t >> 5, kc = t & 31;
#pragma unroll
    for (int u = 0; u < 8; ++u) {
      const int k = kc * 8 + u;
      const fx4* wp = (const fx4*)(W + ((size_t)r * 256 + k) * 256 + o0);
      fx4 w[4] = { wp[0], wp[1], wp[2], wp[3] };
#pragma unroll
      for (int i = 0; i < 16; ++i) {
        const int row = i * 8 + r;               // n'
        const int gs  = (k >> 3) ^ (row & 7);    // swizzled 16B granule
        Wl[row * 256 + gs * 8 + (k & 7)] = f2bf(w[i >> 2][i & 3]);
      }
    }
  }
  __syncthreads();

  const int lane = t & 63, wid = t >> 6;
  const int l15 = lane & 15, lh = lane >> 4;
  const int npb = wid * 32;                      // wave n' base (wave tile 64x32)

  fx4 acc[4][2];
#pragma unroll
  for (int m = 0; m < 4; ++m)
#pragma unroll
    for (int n = 0; n < 2; ++n) acc[m][n] = 0.f;

  // B read addr: byte = row*512 + 16*((4ks+lh) ^ (row&7)) -> Q ^ (64*ks)
  unsigned int qb[2];
#pragma unroll
  for (int n = 0; n < 2; ++n) {
    int row = npb + n * 16 + l15;
    qb[n] = (unsigned)(row * 512 + 16 * (lh ^ (row & 3))) ^ (64u * ((row >> 2) & 1));
  }
  const char* WlB = (const char*)Wl;
  const float* xb = x + (size_t)(j0 + l15) * 256 + lh * 8;

#pragma unroll
  for (int ks = 0; ks < 8; ++ks) {
    s16x8 a[4];
#pragma unroll
    for (int m = 0; m < 4; ++m) {
      const fx4* xp = (const fx4*)(xb + (size_t)m * 16 * 256 + ks * 32);
      fx4 x0 = xp[0], x1 = xp[1];
      s16x8 av;
#pragma unroll
      for (int i = 0; i < 4; ++i) av[i] = (short)f2bf(x0[i]);
#pragma unroll
      for (int i = 0; i < 4; ++i) av[4 + i] = (short)f2bf(x1[i]);
      a[m] = av;
    }
#pragma unroll
    for (int n = 0; n < 2; ++n) {
      s16x8 b = *(const s16x8*)(WlB + (qb[n] ^ (unsigned)(ks * 64)));
#pragma unroll
      for (int m = 0; m < 4; ++m)
        acc[m][n] = __builtin_amdgcn_mfma_f32_16x16x32_bf16(a[m], b, acc[m][n], 0, 0, 0);
    }
  }

  // C[j_l][n'] -> y_t[o0 + n'>>3][(j0+j_l)*8 + (n'&7)]
#pragma unroll
  for (int m = 0; m < 4; ++m)
#pragma unroll
    for (int n = 0; n < 2; ++n)
#pragma unroll
      for (int q = 0; q < 4; ++q) {
        int jl = m * 16 + lh * 4 + q;
        int np = npb + n * 16 + l15;
        int o  = o0 + (np >> 3);
        yt[(size_t)o * 32768 + (size_t)(j0 + jl) * 8 + (np & 7)] = f2bf(acc[m][n][q]);
      }
}

// ---------------- main masked-MFMA GEMM ----------------
// grid (32 mtiles, 2 ntiles, 8 ksplit), 256 thr (4 waves, wave tile 64x64).
// Per step: j-span 16 -> K_eff 128 (4 MFMA k-slices).
// LDS 64 KB: A one-hot [128 i][16 j granules], B [128 o][16 j granules],
// granule ^= (row&15) swizzle; frag read addr = Q ^ (64*ks).
__global__ __launch_bounds__(256, 2) void k_main(const float* __restrict__ A,
                                                 const int*   __restrict__ et,
                                                 const unsigned short* __restrict__ yt,
                                                 float* __restrict__ out) {
  __shared__ unsigned short lds[32768];  // A bytes [0,32768), B bytes [32768,65536)
  const int t = threadIdx.x, lane = t & 63, wid = t >> 6;
  const int i0 = blockIdx.x * 128;
  const int o0 = blockIdx.y * 128;
  const int jb = blockIdx.z * 512;

  // staging: thread -> row si (0..127 for both A-i and B-o), granule half
  const int si  = t >> 1;
  const int sj0 = (t & 1) * 8;
  const float* Ap = A  + (size_t)(i0 + si) * NN + jb + sj0;
  const int*   Ep = et + (size_t)(i0 + si) * NN + jb + sj0;
  const ux4*   Yp = (const ux4*)yt + (size_t)(o0 + si) * 4096 + jb + sj0; // granule = j

  unsigned int aw[8];
#pragma unroll
  for (int u = 0; u < 8; ++u) {
    int jl = sj0 + u;
    aw[u] = (unsigned)(si * 256 + 16 * (jl ^ (si & 15)));
  }

  const int l15 = lane & 15, lh = lane >> 4;
  const int wm = wid >> 1, wn = wid & 1;
  unsigned int Qa[4], Qb[4];
#pragma unroll
  for (int m = 0; m < 4; ++m) {
    int row = wm * 64 + m * 16 + l15;
    Qa[m] = (unsigned)(row * 256 + 16 * (lh ^ (row & 3))) ^ (64u * ((row >> 2) & 3));
  }
#pragma unroll
  for (int n = 0; n < 4; ++n) {
    int row = wn * 64 + n * 16 + l15;
    Qb[n] = (unsigned)(32768 + row * 256 + 16 * (lh ^ (row & 3))) ^ (64u * ((row >> 2) & 3));
  }

  fx4 acc[4][4];
#pragma unroll
  for (int m = 0; m < 4; ++m)
#pragma unroll
    for (int n = 0; n < 4; ++n) acc[m][n] = 0.f;

  // prefetch step 0
  fx4 ra0, ra1; ix4 re0, re1; ux4 ry[8];
  {
    const fx4* ap = (const fx4*)Ap; ra0 = ap[0]; ra1 = ap[1];
    const ix4* ep = (const ix4*)Ep; re0 = ep[0]; re1 = ep[1];
#pragma unroll
    for (int g = 0; g < 8; ++g) ry[g] = Yp[g];
  }

  char* ldsB = (char*)lds;
  for (int s = 0; s < 32; ++s) {
    __syncthreads();  // previous MFMA reads done
    // build one-hot A granules + store B granules
#pragma unroll
    for (int u = 0; u < 8; ++u) {
      float av = (u < 4) ? ra0[u & 3] : ra1[u & 3];
      int   ev = (u < 4) ? re0[u & 3] : re1[u & 3];
      unsigned short hv = f2bf(av);
      unsigned long long sh = ((unsigned long long)hv) << ((ev & 3) * 16);
      unsigned int lo = (unsigned int)sh, hi = (unsigned int)(sh >> 32);
      bool c = (ev < 4);
      ux4 q;
      q.x = c ? lo : 0u; q.y = c ? hi : 0u; q.z = c ? 0u : lo; q.w = c ? 0u : hi;
      *(ux4*)(ldsB + aw[u]) = q;                 // A one-hot
      *(ux4*)(ldsB + aw[u] + 32768) = ry[u];     // B (y_t) granule
    }
    __syncthreads();
    if (s < 31) {  // prefetch next step under MFMA phase
      const fx4* ap = (const fx4*)(Ap + (s + 1) * 16); ra0 = ap[0]; ra1 = ap[1];
      const ix4* ep = (const ix4*)(Ep + (s + 1) * 16); re0 = ep[0]; re1 = ep[1];
#pragma unroll
      for (int g = 0; g < 8; ++g) ry[g] = Yp[(s + 1) * 16 + g];
    }
#pragma unroll
    for (int ks = 0; ks < 4; ++ks) {
      s16x8 a[4], b[4];
#pragma unroll
      for (int m = 0; m < 4; ++m) a[m] = *(const s16x8*)(ldsB + (Qa[m] ^ (unsigned)(ks * 64)));
#pragma unroll
      for (int n = 0; n < 4; ++n) b[n] = *(const s16x8*)(ldsB + (Qb[n] ^ (unsigned)(ks * 64)));
#pragma unroll
      for (int m = 0; m < 4; ++m)
#pragma unroll
        for (int n = 0; n < 4; ++n)
          acc[m][n] = __builtin_amdgcn_mfma_f32_16x16x32_bf16(a[m], b[n], acc[m][n], 0, 0, 0);
    }
  }

  // epilogue: atomic partial add (K-split x8)
#pragma unroll
  for (int m = 0; m < 4; ++m)
#pragma unroll
    for (int n = 0; n < 4; ++n)
#pragma unroll
      for (int q = 0; q < 4; ++q) {
        int gi = i0 + wm * 64 + m * 16 + lh * 4 + q;
        int go = o0 + wn * 64 + n * 16 + l15;
        atomicAdd(out + (size_t)gi * 256 + go, acc[m][n][q]);
      }
}

extern "C" void kernel_launch(void* const* d_in, const int* in_sizes, int n_in,
                              void* d_out, int out_size, void* d_ws, size_t ws_size,
                              hipStream_t stream) {
  const float* x    = (const float*)d_in[0];
  const float* A    = (const float*)d_in[1];
  const int*   et   = (const int*)d_in[2];
  const float* W    = (const float*)d_in[3];
  const float* bias = (const float*)d_in[4];
  float* out = (float*)d_out;
  unsigned short* yt = (unsigned short*)d_ws;  // 256*32768*2 = 16 MB

  k_init<<<dim3(4096), dim3(256), 0, stream>>>(bias, out);
  k_y   <<<dim3(64, 16), dim3(256), 0, stream>>>(x, W, yt);
  k_main<<<dim3(32, 2, 8), dim3(256), 0, stream>>>(A, et, yt, out);
}